// Round 20
// baseline (219.743 us; speedup 1.0000x reference)
//
#include <hip/hip_runtime.h>
#include <stdint.h>

#define B_ 4
#define N_ 2048
#define H_ 16
#define D_ 64
#define QD 1024
#define SCALE 0.125f
#define LOG2E 1.44269504f
#define SC2 (SCALE * LOG2E)

typedef __bf16 bf16x8 __attribute__((ext_vector_type(8)));
typedef float f32x4 __attribute__((ext_vector_type(4)));
typedef float f32x16 __attribute__((ext_vector_type(16)));
typedef unsigned short u16x8 __attribute__((ext_vector_type(8)));
typedef unsigned short u16x4 __attribute__((ext_vector_type(4)));
typedef unsigned short ushort_t;

__device__ __forceinline__ unsigned short f2bf(float f) {
  union { float f; unsigned u; } x; x.f = f;
  unsigned r = (x.u + 0x7fffu + ((x.u >> 16) & 1u)) >> 16;
  return (unsigned short)r;
}

__device__ __forceinline__ void ldg2lds16(const void* g, void* l) {
  __builtin_amdgcn_global_load_lds(
      (const __attribute__((address_space(1))) void*)g,
      (__attribute__((address_space(3))) void*)l, 16, 0, 0);
}

__device__ __forceinline__ ushort_t bfbits(float f) {
  union { __bf16 b; ushort_t u; } x; x.b = (__bf16)f; return x.u;
}

// ---------------- prep: transpose_w ∥ ctx projections (direct, full-K) ----------------
//   wg < 512        : W transpose+convert (was grid (16,16,2))
//   wg in [512,520) : ctx proj: (kv = g>>2, colchunk = g&3), 256 cols/block,
//                     1 col/thread, 4 batch accumulators, serial K (deterministic)
__global__ __launch_bounds__(256) void k_prep(const float* __restrict__ Wq,
    const float* __restrict__ Wo, ushort_t* __restrict__ WqT,
    ushort_t* __restrict__ WoT, const float* __restrict__ ctx,
    const float* __restrict__ Wk, const float* __restrict__ Wv,
    float* __restrict__ kctx, float* __restrict__ vctx) {
  __shared__ __align__(16) float arena[4 * QD];
  const int wg = blockIdx.x;
  const int t = threadIdx.x;
  if (wg < 512) {
    const float* W = (wg >> 8) ? Wo : Wq;
    ushort_t* WT = (wg >> 8) ? WoT : WqT;
    float (*tile)[65] = (float(*)[65])arena;
    int n0 = (wg & 15) * 64, k0 = ((wg >> 4) & 15) * 64;
    int tx = t & 63, ty = t >> 6;
#pragma unroll
    for (int i = 0; i < 64; i += 4)
      tile[ty + i][tx] = W[(size_t)(k0 + ty + i) * QD + n0 + tx];
    __syncthreads();
#pragma unroll
    for (int i = 0; i < 64; i += 4)
      WT[(size_t)(n0 + ty + i) * QD + k0 + tx] = f2bf(tile[tx][ty + i]);
  } else {
    const int g = wg - 512;
    const int kv = g >> 2, cc = g & 3;
    const float* W = kv ? Wv : Wk;
    float* dst = kv ? vctx : kctx;
    // stage ctx [4][1024] fully in LDS
    for (int i = t; i < 4 * QD; i += 256) arena[i] = ctx[i];
    __syncthreads();
    const int col = cc * 256 + t;
    float a0 = 0, a1 = 0, a2 = 0, a3 = 0;
#pragma unroll 4
    for (int k = 0; k < QD; k++) {
      float w = W[(size_t)k * QD + col];
      a0 += arena[0 * QD + k] * w;
      a1 += arena[1 * QD + k] * w;
      a2 += arena[2 * QD + k] * w;
      a3 += arena[3 * QD + k] * w;
    }
    dst[0 * QD + col] = a0;
    dst[1 * QD + col] = a1;
    dst[2 * QD + col] = a2;
    dst[3 * QD + col] = a3;
  }
}

// ---------------- bf16 GEMM v4: BK=64 swizzled + XCD map + qT; A may be fp32 ----
// A_FP32: stage A by reg-load (2x float4) + f2bf + ds_write_b128 to the SAME
// swizzled chunk address the verified layout uses (chunk c -> &As[c*8]).
// Eliminates the separate x->bf16 conversion kernel. B stays global_load_lds.
template <int BF16OUT, int WRITEQT, int A_FP32>
__global__ __launch_bounds__(256) void k_gemm(const void* __restrict__ Av,
    const ushort_t* __restrict__ Bm, ushort_t* __restrict__ Cb, float* __restrict__ Cf,
    const float* __restrict__ bias, ushort_t* __restrict__ qT) {
  __shared__ __align__(16) char arena[WRITEQT ? (128 * 136 * 2) : (128 * 64 * 2 * 2)];
  ushort_t* As = (ushort_t*)arena;
  ushort_t* Bs = (ushort_t*)arena + 128 * 64;
  const int wg = blockIdx.x;
  const int by = (wg & 7) * 8 + ((wg >> 3) & 7);
  const int bx = wg >> 6;
  const int t = threadIdx.x;
  const int w = t >> 6, l = t & 63;
  const int wr = w >> 1, wc = w & 1;
  const int lr = l & 15, lg = l >> 4;
  const int m0 = by * 128, n0 = bx * 128;
  const ushort_t* Ab = (const ushort_t*)Av;
  const float* Af = (const float*)Av;
  f32x4 acc[4][4] = {};
  for (int k0 = 0; k0 < QD; k0 += 64) {
#pragma unroll
    for (int rep = 0; rep < 4; rep++) {
      int c = t + rep * 256;
      int row = c >> 3, c0 = 8 * ((c & 7) ^ (row & 7));
      if constexpr (A_FP32) {
        const float* src = &Af[(size_t)(m0 + row) * QD + k0 + c0];
        float4 f0 = *(const float4*)src, f1 = *(const float4*)(src + 4);
        u16x8 v;
        v[0] = f2bf(f0.x); v[1] = f2bf(f0.y); v[2] = f2bf(f0.z); v[3] = f2bf(f0.w);
        v[4] = f2bf(f1.x); v[5] = f2bf(f1.y); v[6] = f2bf(f1.z); v[7] = f2bf(f1.w);
        *(u16x8*)&As[c * 8] = v;
      } else {
        ldg2lds16(&Ab[(size_t)(m0 + row) * QD + k0 + c0], &As[c * 8]);
      }
      ldg2lds16(&Bm[(size_t)(n0 + row) * QD + k0 + c0], &Bs[c * 8]);
    }
    __syncthreads();
#pragma unroll
    for (int kk = 0; kk < 2; kk++) {
      bf16x8 af[4], bfr[4];
#pragma unroll
      for (int m = 0; m < 4; m++) {
        int row = wr * 64 + m * 16 + lr;
        af[m] = *(const bf16x8*)((const char*)As + row * 128 +
                                 (((kk * 4 + lg) ^ (row & 7)) << 4));
      }
#pragma unroll
      for (int n = 0; n < 4; n++) {
        int row = wc * 64 + n * 16 + lr;
        bfr[n] = *(const bf16x8*)((const char*)Bs + row * 128 +
                                  (((kk * 4 + lg) ^ (row & 7)) << 4));
      }
#pragma unroll
      for (int m = 0; m < 4; m++)
#pragma unroll
        for (int n = 0; n < 4; n++)
          acc[m][n] = __builtin_amdgcn_mfma_f32_16x16x32_bf16(af[m], bfr[n], acc[m][n], 0, 0, 0);
    }
    __syncthreads();
  }
#pragma unroll
  for (int m = 0; m < 4; m++) {
    int row = m0 + wr * 64 + m * 16 + lg * 4;
#pragma unroll
    for (int n = 0; n < 4; n++) {
      int col = n0 + wc * 64 + n * 16 + lr;
#pragma unroll
      for (int j = 0; j < 4; j++) {
        float v = acc[m][n][j];
        if constexpr (BF16OUT) {
          Cb[(size_t)(row + j) * QD + col] = f2bf(v);
        } else {
          Cf[(size_t)(row + j) * QD + col] = v + bias[col];
        }
      }
    }
  }
  if constexpr (WRITEQT) {
    ushort_t* T2 = (ushort_t*)arena;  // [col][row], stride 136
#pragma unroll
    for (int m = 0; m < 4; m++) {
      int rowl = wr * 64 + m * 16 + lg * 4;
#pragma unroll
      for (int n = 0; n < 4; n++) {
        int col = wc * 64 + n * 16 + lr;
        u16x4 v;
#pragma unroll
        for (int j = 0; j < 4; j++) v[j] = f2bf(acc[m][n][j]);
        *(u16x4*)&T2[col * 136 + rowl] = v;
      }
    }
    __syncthreads();
    const int c = t & 127, r0 = (t >> 7) * 64;
    const int h = (n0 + c) >> 6, d = (n0 + c) & 63;
    const int b = m0 >> 11, nloc = (m0 & 2047) + r0;
    ushort_t* dst = qT + ((size_t)(b * 16 + h) * 64 + d) * (size_t)N_ + nloc;
#pragma unroll
    for (int i = 0; i < 8; i++)
      *(u16x8*)(dst + i * 8) = *(const u16x8*)&T2[c * 136 + r0 + i * 8];
  }
}

// ---------------- flash attention v14 (R19, passing): 8-wave blocks ----------------
__global__ __launch_bounds__(512, 4) void k_attn14(
    const ushort_t* __restrict__ q, const ushort_t* __restrict__ qT,
    const float* __restrict__ kctx, const float* __restrict__ vctx,
    ushort_t* __restrict__ att) {
  const int wg = blockIdx.x;
  const int k8 = wg >> 6;                             // 0..7
  const int s = (k8 < 4) ? k8 : (11 - k8);            // strip 0..7
  const int bh = ((wg & 7) << 3) | ((wg >> 3) & 7);   // 0..63, XCD-grouped
  const int b = bh >> 4, h = bh & 15;
  const int t = threadIdx.x, w = t >> 6, l = t & 63;
  const int lq = l & 31, hi = l >> 5;
  const int wq0 = s * 256 + w * 32;

  __shared__ __align__(128) ushort_t Ks[2][2][4096];  // [pair][sub]
  __shared__ __align__(128) ushort_t Vs[2][2][4096];

  const ushort_t* qbase = q + (size_t)b * N_ * QD + h * D_;
  const ushort_t* qtb = qT + (size_t)bh * D_ * N_;
  const float* kc = kctx + bh * D_;
  const float* vc = vctx + bh * D_;

  const int srow = t >> 3;                            // 0..63
  const int scol = 8 * ((t & 7) ^ ((t >> 3) & 7));

  const int NI = 2 * s + 2;

  const ushort_t* stK = qbase + (size_t)srow * QD + scol;
  const ushort_t* stV = qtb + (size_t)srow * N_ + scol;

  auto stage = [&](int pr, int j) {
    ldg2lds16(stK, &Ks[pr][j][t * 8]);
    ldg2lds16(stV, &Vs[pr][j][t * 8]);
    stK += (size_t)64 * QD;
    stV += 64;
  };

  stage(0, 0);
  stage(0, 1);

  bf16x8 qf[4];
#pragma unroll
  for (int kk = 0; kk < 4; kk++) {
    qf[kk] = *(const bf16x8*)&qbase[(size_t)(wq0 + lq) * QD + kk * 16 + hi * 8];
#pragma unroll
    for (int j = 0; j < 8; j++)
      qf[kk][j] = (__bf16)((float)qf[kk][j] * SC2);
  }

  float ew, lacc;
  f32x16 oacc[2];
  {
    float dot = 0.f;
#pragma unroll
    for (int kk = 0; kk < 4; kk++)
#pragma unroll
      for (int j = 0; j < 8; j++)
        dot += (float)qf[kk][j] * kc[kk * 16 + hi * 8 + j];
    dot += __shfl_xor(dot, 32);
    ew = __builtin_exp2f(dot);
    lacc = 0.0f;
#pragma unroll
    for (int dt = 0; dt < 2; dt++)
#pragma unroll
      for (int r = 0; r < 16; r++)
        oacc[dt][r] = vc[dt * 32 + (r & 3) + 8 * (r >> 2) + 4 * hi] * ew;
  }

  auto body = [&](int tt, const char* ksb, const char* vsb) {
    const int j0 = tt * 64;
    if (j0 > wq0 + 31) return;

    f32x16 p[2];
    __builtin_amdgcn_s_setprio(1);
#pragma unroll
    for (int kb = 0; kb < 2; kb++) {
      f32x16 acc = {};
#pragma unroll
      for (int kk = 0; kk < 4; kk++) {
        bf16x8 kf = *(const bf16x8*)(ksb + (l & 31) * 128 + kb * 4096 +
                                     (((kk * 2 + hi) ^ (l & 7)) << 4));
        acc = __builtin_amdgcn_mfma_f32_32x32x16_bf16(kf, qf[kk], acc, 0, 0, 0);
      }
      p[kb] = acc;
    }
    __builtin_amdgcn_s_setprio(0);

    if (j0 + 63 > wq0) {
      const int qrel = wq0 - j0 + lq;
#pragma unroll
      for (int kb = 0; kb < 2; kb++)
#pragma unroll
        for (int r = 0; r < 16; r++) {
          int key = kb * 32 + (r & 3) + 8 * (r >> 2) + 4 * hi;
          if (key > qrel) p[kb][r] = -1e30f;
        }
    }

#pragma unroll
    for (int kb = 0; kb < 2; kb++)
#pragma unroll
      for (int r = 0; r < 16; r++)
        p[kb][r] = __builtin_exp2f(p[kb][r]);
    float s8[8];
#pragma unroll
    for (int r = 0; r < 8; r++)
      s8[r] = (p[0][r] + p[0][r + 8]) + (p[1][r] + p[1][r + 8]);
    float s4a = s8[0] + s8[4], s4b = s8[1] + s8[5];
    float s4c = s8[2] + s8[6], s4d = s8[3] + s8[7];
    lacc += (s4a + s4b) + (s4c + s4d);

#pragma unroll
    for (int kb = 0; kb < 2; kb++) {
      unsigned u[8];
#pragma unroll
      for (int i = 0; i < 8; i++) {
        float lo = p[kb][2 * i], hi2 = p[kb][2 * i + 1];
        asm("v_cvt_pk_bf16_f32 %0, %1, %2" : "=v"(u[i]) : "v"(lo), "v"(hi2));
      }
      asm("v_permlane32_swap_b32 %0, %1" : "+v"(u[0]), "+v"(u[2]));
      asm("v_permlane32_swap_b32 %0, %1" : "+v"(u[1]), "+v"(u[3]));
      asm("v_permlane32_swap_b32 %0, %1" : "+v"(u[4]), "+v"(u[6]));
      asm("v_permlane32_swap_b32 %0, %1" : "+v"(u[5]), "+v"(u[7]));
      union { unsigned u4[4]; bf16x8 v; } pf0, pf1;
      pf0.u4[0] = u[0]; pf0.u4[1] = u[1]; pf0.u4[2] = u[2]; pf0.u4[3] = u[3];
      pf1.u4[0] = u[4]; pf1.u4[1] = u[5]; pf1.u4[2] = u[6]; pf1.u4[3] = u[7];
      __builtin_amdgcn_s_setprio(1);
#pragma unroll
      for (int ks = 0; ks < 2; ks++) {
        const bf16x8 pf = ks ? pf1.v : pf0.v;
#pragma unroll
        for (int dt = 0; dt < 2; dt++) {
          bf16x8 vf = *(const bf16x8*)(vsb + (l & 31) * 128 + dt * 4096 +
                                       (((kb * 4 + ks * 2 + hi) ^ (l & 7)) << 4));
          oacc[dt] = __builtin_amdgcn_mfma_f32_32x32x16_bf16(vf, pf, oacc[dt], 0, 0, 0);
        }
      }
      __builtin_amdgcn_s_setprio(0);
    }
  };

  for (int it = 0; it < NI; ++it) {
    const int pr = it & 1;
    if (it + 1 < NI) {
      stage(pr ^ 1, 0);
      stage(pr ^ 1, 1);
      asm volatile("s_waitcnt vmcnt(4)" ::: "memory");
    } else {
      asm volatile("s_waitcnt vmcnt(0)" ::: "memory");
    }
    __builtin_amdgcn_s_barrier();

    body(2 * it,     (const char*)&Ks[pr][0][0], (const char*)&Vs[pr][0][0]);
    body(2 * it + 1, (const char*)&Ks[pr][1][0], (const char*)&Vs[pr][1][0]);

    __builtin_amdgcn_s_barrier();
  }

  const float lsum = ew + lacc + __shfl_xor(lacc, 32);
  const float inv = 1.0f / lsum;
  ushort_t* ob = att + (size_t)b * N_ * QD + (size_t)(wq0 + lq) * QD + h * D_;
#pragma unroll
  for (int dt = 0; dt < 2; dt++)
#pragma unroll
    for (int rq = 0; rq < 4; rq++) {
      union { ushort_t s4[4]; unsigned long long v; } o;
#pragma unroll
      for (int e = 0; e < 4; e++) o.s4[e] = bfbits(oacc[dt][rq * 4 + e] * inv);
      *(unsigned long long*)(ob + dt * 32 + 8 * rq + 4 * hi) = o.v;
    }
}

extern "C" void kernel_launch(void* const* d_in, const int* in_sizes, int n_in,
                              void* d_out, int out_size, void* d_ws, size_t ws_size,
                              hipStream_t stream) {
  const float* x = (const float*)d_in[0];
  const float* ctx = (const float*)d_in[1];
  const float* Wq = (const float*)d_in[2];
  const float* Wk = (const float*)d_in[3];
  const float* Wv = (const float*)d_in[4];
  const float* Wo = (const float*)d_in[5];
  const float* bo = (const float*)d_in[6];
  float* out = (float*)d_out;

  char* ws = (char*)d_ws;
  size_t off = 0;
  ushort_t* qb = (ushort_t*)(ws + off);   off += (size_t)8192 * 1024 * 2;
  ushort_t* attb = (ushort_t*)(ws + off); off += (size_t)8192 * 1024 * 2;
  ushort_t* WqT = (ushort_t*)(ws + off);  off += (size_t)1024 * 1024 * 2;
  ushort_t* WoT = (ushort_t*)(ws + off);  off += (size_t)1024 * 1024 * 2;
  float* kctx = (float*)(ws + off);       off += (size_t)4096 * 4;
  float* vctx = (float*)(ws + off);       off += (size_t)4096 * 4;
  ushort_t* qT2 = (ushort_t*)(ws + off);  off += (size_t)8192 * 1024 * 2;

  k_prep<<<dim3(520), dim3(256), 0, stream>>>(Wq, Wo, WqT, WoT, ctx, Wk, Wv,
                                              kctx, vctx);
  k_gemm<1, 1, 1><<<dim3(512), dim3(256), 0, stream>>>(x, WqT, qb, nullptr, nullptr, qT2);
  k_attn14<<<dim3(512), dim3(512), 0, stream>>>(qb, qT2, kctx, vctx, attb);
  k_gemm<0, 0, 0><<<dim3(512), dim3(256), 0, stream>>>(attb, WoT, nullptr, out, bo, nullptr);
}

// Round 21
// 141.357 us; speedup vs baseline: 1.5545x; 1.5545x over previous
//
#include <hip/hip_runtime.h>
#include <stdint.h>

#define B_ 4
#define N_ 2048
#define H_ 16
#define D_ 64
#define QD 1024
#define SCALE 0.125f
#define LOG2E 1.44269504f
#define SC2 (SCALE * LOG2E)

typedef __bf16 bf16x8 __attribute__((ext_vector_type(8)));
typedef float f32x4 __attribute__((ext_vector_type(4)));
typedef float f32x16 __attribute__((ext_vector_type(16)));
typedef unsigned short u16x8 __attribute__((ext_vector_type(8)));
typedef unsigned short u16x4 __attribute__((ext_vector_type(4)));
typedef unsigned short ushort_t;

__device__ __forceinline__ unsigned short f2bf(float f) {
  union { float f; unsigned u; } x; x.f = f;
  unsigned r = (x.u + 0x7fffu + ((x.u >> 16) & 1u)) >> 16;
  return (unsigned short)r;
}

__device__ __forceinline__ void ldg2lds16(const void* g, void* l) {
  __builtin_amdgcn_global_load_lds(
      (const __attribute__((address_space(1))) void*)g,
      (__attribute__((address_space(3))) void*)l, 16, 0, 0);
}

__device__ __forceinline__ ushort_t bfbits(float f) {
  union { __bf16 b; ushort_t u; } x; x.b = (__bf16)f; return x.u;
}

// ---------------- prep: transpose_w ∥ ctx split-K partials (R16-proven) ----------------
//   wg < 512        : W transpose+convert
//   wg in [512,576) : ctx partials (ich = g&3, ks = (g>>2)&7, kv = g>>5)
__global__ __launch_bounds__(256) void k_prep(const float* __restrict__ Wq,
    const float* __restrict__ Wo, ushort_t* __restrict__ WqT,
    ushort_t* __restrict__ WoT, const float* __restrict__ ctx,
    const float* __restrict__ Wk, const float* __restrict__ Wv,
    float* __restrict__ part) {
  __shared__ __align__(16) char arena[64 * 65 * 4];
  const int wg = blockIdx.x;
  const int t = threadIdx.x;
  if (wg < 512) {
    const float* W = (wg >> 8) ? Wo : Wq;
    ushort_t* WT = (wg >> 8) ? WoT : WqT;
    float (*tile)[65] = (float(*)[65])arena;
    int n0 = (wg & 15) * 64, k0 = ((wg >> 4) & 15) * 64;
    int tx = t & 63, ty = t >> 6;
#pragma unroll
    for (int i = 0; i < 64; i += 4)
      tile[ty + i][tx] = W[(size_t)(k0 + ty + i) * QD + n0 + tx];
    __syncthreads();
#pragma unroll
    for (int i = 0; i < 64; i += 4)
      WT[(size_t)(n0 + ty + i) * QD + k0 + tx] = f2bf(tile[tx][ty + i]);
  } else {
    const int g = wg - 512;
    const int ich = g & 3, ks = (g >> 2) & 7, kv = g >> 5;
    const float* W = kv ? Wv : Wk;
    float (*cs)[128] = (float(*)[128])arena;
    for (int i = t; i < B_ * 128; i += 256)
      cs[i >> 7][i & 127] = ctx[(size_t)(i >> 7) * QD + ks * 128 + (i & 127)];
    __syncthreads();
    int col = ich * 256 + t;
    float a0 = 0, a1 = 0, a2 = 0, a3 = 0;
    for (int k = 0; k < 128; k++) {
      float w = W[(size_t)(ks * 128 + k) * QD + col];
      a0 += cs[0][k] * w; a1 += cs[1][k] * w; a2 += cs[2][k] * w; a3 += cs[3][k] * w;
    }
    float* p = part + (size_t)(ks * 2 + kv) * (B_ * QD);
    p[0 * QD + col] = a0; p[1 * QD + col] = a1; p[2 * QD + col] = a2; p[3 * QD + col] = a3;
  }
}

__global__ __launch_bounds__(256) void k_ctx_reduce(const float* __restrict__ part,
    float* __restrict__ kctx, float* __restrict__ vctx) {
  int idx = blockIdx.x * 256 + threadIdx.x;
  int kv = idx >> 12;
  int rest = idx & 4095;
  float acc = 0;
  for (int ks = 0; ks < 8; ks++) acc += part[(size_t)(ks * 2 + kv) * 4096 + rest];
  (kv ? vctx : kctx)[rest] = acc;
}

// ---------------- bf16 GEMM v4 (R20 structure): BK=64 swizzled + XCD map + qT; fp32 A ----
template <int BF16OUT, int WRITEQT, int A_FP32>
__global__ __launch_bounds__(256) void k_gemm(const void* __restrict__ Av,
    const ushort_t* __restrict__ Bm, ushort_t* __restrict__ Cb, float* __restrict__ Cf,
    const float* __restrict__ bias, ushort_t* __restrict__ qT) {
  __shared__ __align__(16) char arena[WRITEQT ? (128 * 136 * 2) : (128 * 64 * 2 * 2)];
  ushort_t* As = (ushort_t*)arena;
  ushort_t* Bs = (ushort_t*)arena + 128 * 64;
  const int wg = blockIdx.x;
  const int by = (wg & 7) * 8 + ((wg >> 3) & 7);
  const int bx = wg >> 6;
  const int t = threadIdx.x;
  const int w = t >> 6, l = t & 63;
  const int wr = w >> 1, wc = w & 1;
  const int lr = l & 15, lg = l >> 4;
  const int m0 = by * 128, n0 = bx * 128;
  const ushort_t* Ab = (const ushort_t*)Av;
  const float* Af = (const float*)Av;
  f32x4 acc[4][4] = {};
  for (int k0 = 0; k0 < QD; k0 += 64) {
#pragma unroll
    for (int rep = 0; rep < 4; rep++) {
      int c = t + rep * 256;
      int row = c >> 3, c0 = 8 * ((c & 7) ^ (row & 7));
      if constexpr (A_FP32) {
        const float* src = &Af[(size_t)(m0 + row) * QD + k0 + c0];
        float4 f0 = *(const float4*)src, f1 = *(const float4*)(src + 4);
        u16x8 v;
        v[0] = f2bf(f0.x); v[1] = f2bf(f0.y); v[2] = f2bf(f0.z); v[3] = f2bf(f0.w);
        v[4] = f2bf(f1.x); v[5] = f2bf(f1.y); v[6] = f2bf(f1.z); v[7] = f2bf(f1.w);
        *(u16x8*)&As[c * 8] = v;
      } else {
        ldg2lds16(&Ab[(size_t)(m0 + row) * QD + k0 + c0], &As[c * 8]);
      }
      ldg2lds16(&Bm[(size_t)(n0 + row) * QD + k0 + c0], &Bs[c * 8]);
    }
    __syncthreads();
#pragma unroll
    for (int kk = 0; kk < 2; kk++) {
      bf16x8 af[4], bfr[4];
#pragma unroll
      for (int m = 0; m < 4; m++) {
        int row = wr * 64 + m * 16 + lr;
        af[m] = *(const bf16x8*)((const char*)As + row * 128 +
                                 (((kk * 4 + lg) ^ (row & 7)) << 4));
      }
#pragma unroll
      for (int n = 0; n < 4; n++) {
        int row = wc * 64 + n * 16 + lr;
        bfr[n] = *(const bf16x8*)((const char*)Bs + row * 128 +
                                  (((kk * 4 + lg) ^ (row & 7)) << 4));
      }
#pragma unroll
      for (int m = 0; m < 4; m++)
#pragma unroll
        for (int n = 0; n < 4; n++)
          acc[m][n] = __builtin_amdgcn_mfma_f32_16x16x32_bf16(af[m], bfr[n], acc[m][n], 0, 0, 0);
    }
    __syncthreads();
  }
#pragma unroll
  for (int m = 0; m < 4; m++) {
    int row = m0 + wr * 64 + m * 16 + lg * 4;
#pragma unroll
    for (int n = 0; n < 4; n++) {
      int col = n0 + wc * 64 + n * 16 + lr;
#pragma unroll
      for (int j = 0; j < 4; j++) {
        float v = acc[m][n][j];
        if constexpr (BF16OUT) {
          Cb[(size_t)(row + j) * QD + col] = f2bf(v);
        } else {
          Cf[(size_t)(row + j) * QD + col] = v + bias[col];
        }
      }
    }
  }
  if constexpr (WRITEQT) {
    ushort_t* T2 = (ushort_t*)arena;  // [col][row], stride 136
#pragma unroll
    for (int m = 0; m < 4; m++) {
      int rowl = wr * 64 + m * 16 + lg * 4;
#pragma unroll
      for (int n = 0; n < 4; n++) {
        int col = wc * 64 + n * 16 + lr;
        u16x4 v;
#pragma unroll
        for (int j = 0; j < 4; j++) v[j] = f2bf(acc[m][n][j]);
        *(u16x4*)&T2[col * 136 + rowl] = v;
      }
    }
    __syncthreads();
    const int c = t & 127, r0 = (t >> 7) * 64;
    const int h = (n0 + c) >> 6, d = (n0 + c) & 63;
    const int b = m0 >> 11, nloc = (m0 & 2047) + r0;
    ushort_t* dst = qT + ((size_t)(b * 16 + h) * 64 + d) * (size_t)N_ + nloc;
#pragma unroll
    for (int i = 0; i < 8; i++)
      *(u16x8*)(dst + i * 8) = *(const u16x8*)&T2[c * 136 + r0 + i * 8];
  }
}

// ---------------- flash attention v14 (R19, passing): 8-wave blocks ----------------
__global__ __launch_bounds__(512, 4) void k_attn14(
    const ushort_t* __restrict__ q, const ushort_t* __restrict__ qT,
    const float* __restrict__ kctx, const float* __restrict__ vctx,
    ushort_t* __restrict__ att) {
  const int wg = blockIdx.x;
  const int k8 = wg >> 6;                             // 0..7
  const int s = (k8 < 4) ? k8 : (11 - k8);            // strip 0..7
  const int bh = ((wg & 7) << 3) | ((wg >> 3) & 7);   // 0..63, XCD-grouped
  const int b = bh >> 4, h = bh & 15;
  const int t = threadIdx.x, w = t >> 6, l = t & 63;
  const int lq = l & 31, hi = l >> 5;
  const int wq0 = s * 256 + w * 32;

  __shared__ __align__(128) ushort_t Ks[2][2][4096];  // [pair][sub]
  __shared__ __align__(128) ushort_t Vs[2][2][4096];

  const ushort_t* qbase = q + (size_t)b * N_ * QD + h * D_;
  const ushort_t* qtb = qT + (size_t)bh * D_ * N_;
  const float* kc = kctx + bh * D_;
  const float* vc = vctx + bh * D_;

  const int srow = t >> 3;                            // 0..63
  const int scol = 8 * ((t & 7) ^ ((t >> 3) & 7));

  const int NI = 2 * s + 2;

  const ushort_t* stK = qbase + (size_t)srow * QD + scol;
  const ushort_t* stV = qtb + (size_t)srow * N_ + scol;

  auto stage = [&](int pr, int j) {
    ldg2lds16(stK, &Ks[pr][j][t * 8]);
    ldg2lds16(stV, &Vs[pr][j][t * 8]);
    stK += (size_t)64 * QD;
    stV += 64;
  };

  stage(0, 0);
  stage(0, 1);

  bf16x8 qf[4];
#pragma unroll
  for (int kk = 0; kk < 4; kk++) {
    qf[kk] = *(const bf16x8*)&qbase[(size_t)(wq0 + lq) * QD + kk * 16 + hi * 8];
#pragma unroll
    for (int j = 0; j < 8; j++)
      qf[kk][j] = (__bf16)((float)qf[kk][j] * SC2);
  }

  float ew, lacc;
  f32x16 oacc[2];
  {
    float dot = 0.f;
#pragma unroll
    for (int kk = 0; kk < 4; kk++)
#pragma unroll
      for (int j = 0; j < 8; j++)
        dot += (float)qf[kk][j] * kc[kk * 16 + hi * 8 + j];
    dot += __shfl_xor(dot, 32);
    ew = __builtin_exp2f(dot);
    lacc = 0.0f;
#pragma unroll
    for (int dt = 0; dt < 2; dt++)
#pragma unroll
      for (int r = 0; r < 16; r++)
        oacc[dt][r] = vc[dt * 32 + (r & 3) + 8 * (r >> 2) + 4 * hi] * ew;
  }

  auto body = [&](int tt, const char* ksb, const char* vsb) {
    const int j0 = tt * 64;
    if (j0 > wq0 + 31) return;

    f32x16 p[2];
    __builtin_amdgcn_s_setprio(1);
#pragma unroll
    for (int kb = 0; kb < 2; kb++) {
      f32x16 acc = {};
#pragma unroll
      for (int kk = 0; kk < 4; kk++) {
        bf16x8 kf = *(const bf16x8*)(ksb + (l & 31) * 128 + kb * 4096 +
                                     (((kk * 2 + hi) ^ (l & 7)) << 4));
        acc = __builtin_amdgcn_mfma_f32_32x32x16_bf16(kf, qf[kk], acc, 0, 0, 0);
      }
      p[kb] = acc;
    }
    __builtin_amdgcn_s_setprio(0);

    if (j0 + 63 > wq0) {
      const int qrel = wq0 - j0 + lq;
#pragma unroll
      for (int kb = 0; kb < 2; kb++)
#pragma unroll
        for (int r = 0; r < 16; r++) {
          int key = kb * 32 + (r & 3) + 8 * (r >> 2) + 4 * hi;
          if (key > qrel) p[kb][r] = -1e30f;
        }
    }

#pragma unroll
    for (int kb = 0; kb < 2; kb++)
#pragma unroll
      for (int r = 0; r < 16; r++)
        p[kb][r] = __builtin_exp2f(p[kb][r]);
    float s8[8];
#pragma unroll
    for (int r = 0; r < 8; r++)
      s8[r] = (p[0][r] + p[0][r + 8]) + (p[1][r] + p[1][r + 8]);
    float s4a = s8[0] + s8[4], s4b = s8[1] + s8[5];
    float s4c = s8[2] + s8[6], s4d = s8[3] + s8[7];
    lacc += (s4a + s4b) + (s4c + s4d);

#pragma unroll
    for (int kb = 0; kb < 2; kb++) {
      unsigned u[8];
#pragma unroll
      for (int i = 0; i < 8; i++) {
        float lo = p[kb][2 * i], hi2 = p[kb][2 * i + 1];
        asm("v_cvt_pk_bf16_f32 %0, %1, %2" : "=v"(u[i]) : "v"(lo), "v"(hi2));
      }
      asm("v_permlane32_swap_b32 %0, %1" : "+v"(u[0]), "+v"(u[2]));
      asm("v_permlane32_swap_b32 %0, %1" : "+v"(u[1]), "+v"(u[3]));
      asm("v_permlane32_swap_b32 %0, %1" : "+v"(u[4]), "+v"(u[6]));
      asm("v_permlane32_swap_b32 %0, %1" : "+v"(u[5]), "+v"(u[7]));
      union { unsigned u4[4]; bf16x8 v; } pf0, pf1;
      pf0.u4[0] = u[0]; pf0.u4[1] = u[1]; pf0.u4[2] = u[2]; pf0.u4[3] = u[3];
      pf1.u4[0] = u[4]; pf1.u4[1] = u[5]; pf1.u4[2] = u[6]; pf1.u4[3] = u[7];
      __builtin_amdgcn_s_setprio(1);
#pragma unroll
      for (int ks = 0; ks < 2; ks++) {
        const bf16x8 pf = ks ? pf1.v : pf0.v;
#pragma unroll
        for (int dt = 0; dt < 2; dt++) {
          bf16x8 vf = *(const bf16x8*)(vsb + (l & 31) * 128 + dt * 4096 +
                                       (((kb * 4 + ks * 2 + hi) ^ (l & 7)) << 4));
          oacc[dt] = __builtin_amdgcn_mfma_f32_32x32x16_bf16(vf, pf, oacc[dt], 0, 0, 0);
        }
      }
      __builtin_amdgcn_s_setprio(0);
    }
  };

  for (int it = 0; it < NI; ++it) {
    const int pr = it & 1;
    if (it + 1 < NI) {
      stage(pr ^ 1, 0);
      stage(pr ^ 1, 1);
      asm volatile("s_waitcnt vmcnt(4)" ::: "memory");
    } else {
      asm volatile("s_waitcnt vmcnt(0)" ::: "memory");
    }
    __builtin_amdgcn_s_barrier();

    body(2 * it,     (const char*)&Ks[pr][0][0], (const char*)&Vs[pr][0][0]);
    body(2 * it + 1, (const char*)&Ks[pr][1][0], (const char*)&Vs[pr][1][0]);

    __builtin_amdgcn_s_barrier();
  }

  const float lsum = ew + lacc + __shfl_xor(lacc, 32);
  const float inv = 1.0f / lsum;
  ushort_t* ob = att + (size_t)b * N_ * QD + (size_t)(wq0 + lq) * QD + h * D_;
#pragma unroll
  for (int dt = 0; dt < 2; dt++)
#pragma unroll
    for (int rq = 0; rq < 4; rq++) {
      union { ushort_t s4[4]; unsigned long long v; } o;
#pragma unroll
      for (int e = 0; e < 4; e++) o.s4[e] = bfbits(oacc[dt][rq * 4 + e] * inv);
      *(unsigned long long*)(ob + dt * 32 + 8 * rq + 4 * hi) = o.v;
    }
}

extern "C" void kernel_launch(void* const* d_in, const int* in_sizes, int n_in,
                              void* d_out, int out_size, void* d_ws, size_t ws_size,
                              hipStream_t stream) {
  const float* x = (const float*)d_in[0];
  const float* ctx = (const float*)d_in[1];
  const float* Wq = (const float*)d_in[2];
  const float* Wk = (const float*)d_in[3];
  const float* Wv = (const float*)d_in[4];
  const float* Wo = (const float*)d_in[5];
  const float* bo = (const float*)d_in[6];
  float* out = (float*)d_out;

  char* ws = (char*)d_ws;
  size_t off = 0;
  ushort_t* qb = (ushort_t*)(ws + off);   off += (size_t)8192 * 1024 * 2;
  ushort_t* attb = (ushort_t*)(ws + off); off += (size_t)8192 * 1024 * 2;
  ushort_t* WqT = (ushort_t*)(ws + off);  off += (size_t)1024 * 1024 * 2;
  ushort_t* WoT = (ushort_t*)(ws + off);  off += (size_t)1024 * 1024 * 2;
  float* kctx = (float*)(ws + off);       off += (size_t)4096 * 4;
  float* vctx = (float*)(ws + off);       off += (size_t)4096 * 4;
  float* part = (float*)(ws + off);       off += (size_t)16 * 4096 * 4;
  ushort_t* qT2 = (ushort_t*)(ws + off);  off += (size_t)8192 * 1024 * 2;

  k_prep<<<dim3(576), dim3(256), 0, stream>>>(Wq, Wo, WqT, WoT, ctx, Wk, Wv, part);
  k_ctx_reduce<<<dim3(32), dim3(256), 0, stream>>>(part, kctx, vctx);
  k_gemm<1, 1, 1><<<dim3(512), dim3(256), 0, stream>>>(x, WqT, qb, nullptr, nullptr, qT2);
  k_attn14<<<dim3(512), dim3(512), 0, stream>>>(qb, qT2, kctx, vctx, attb);
  k_gemm<0, 0, 0><<<dim3(512), dim3(256), 0, stream>>>(attb, WoT, nullptr, out, bo, nullptr);
}

// Round 22
// 136.654 us; speedup vs baseline: 1.6080x; 1.0344x over previous
//
#include <hip/hip_runtime.h>
#include <stdint.h>

#define B_ 4
#define N_ 2048
#define H_ 16
#define D_ 64
#define QD 1024
#define SCALE 0.125f
#define LOG2E 1.44269504f
#define SC2 (SCALE * LOG2E)

typedef __bf16 bf16x8 __attribute__((ext_vector_type(8)));
typedef float f32x4 __attribute__((ext_vector_type(4)));
typedef float f32x16 __attribute__((ext_vector_type(16)));
typedef unsigned short u16x8 __attribute__((ext_vector_type(8)));
typedef unsigned short u16x4 __attribute__((ext_vector_type(4)));
typedef unsigned short ushort_t;

__device__ __forceinline__ unsigned short f2bf(float f) {
  union { float f; unsigned u; } x; x.f = f;
  unsigned r = (x.u + 0x7fffu + ((x.u >> 16) & 1u)) >> 16;
  return (unsigned short)r;
}

__device__ __forceinline__ void ldg2lds16(const void* g, void* l) {
  __builtin_amdgcn_global_load_lds(
      (const __attribute__((address_space(1))) void*)g,
      (__attribute__((address_space(3))) void*)l, 16, 0, 0);
}

__device__ __forceinline__ ushort_t bfbits(float f) {
  union { __bf16 b; ushort_t u; } x; x.b = (__bf16)f; return x.u;
}

// ---------------- prep mega-kernel: cvt ∥ transpose_w ∥ ctx_partial (R18) ----------------
__global__ __launch_bounds__(256) void k_prep(const float* __restrict__ x,
    ushort_t* __restrict__ xb, const float* __restrict__ Wq,
    const float* __restrict__ Wo, ushort_t* __restrict__ WqT,
    ushort_t* __restrict__ WoT, const float* __restrict__ ctx,
    const float* __restrict__ Wk, const float* __restrict__ Wv,
    float* __restrict__ part) {
  __shared__ __align__(16) char arena[64 * 65 * 4];
  const int wg = blockIdx.x;
  const int t = threadIdx.x;
  if (wg < 4096) {
    int i = wg * 256 + t;
    const float4* p = (const float4*)x + (size_t)i * 2;
    float4 a = p[0], b = p[1];
    u16x8 r;
    r[0] = f2bf(a.x); r[1] = f2bf(a.y); r[2] = f2bf(a.z); r[3] = f2bf(a.w);
    r[4] = f2bf(b.x); r[5] = f2bf(b.y); r[6] = f2bf(b.z); r[7] = f2bf(b.w);
    *((u16x8*)xb + i) = r;
  } else if (wg < 4608) {
    const int wgl = wg - 4096;
    const float* W = (wgl >> 8) ? Wo : Wq;
    ushort_t* WT = (wgl >> 8) ? WoT : WqT;
    float (*tile)[65] = (float(*)[65])arena;
    int n0 = (wgl & 15) * 64, k0 = ((wgl >> 4) & 15) * 64;
    int tx = t & 63, ty = t >> 6;
#pragma unroll
    for (int i = 0; i < 64; i += 4)
      tile[ty + i][tx] = W[(size_t)(k0 + ty + i) * QD + n0 + tx];
    __syncthreads();
#pragma unroll
    for (int i = 0; i < 64; i += 4)
      WT[(size_t)(n0 + ty + i) * QD + k0 + tx] = f2bf(tile[tx][ty + i]);
  } else {
    const int wgl = wg - 4608;
    const int ich = wgl & 3, ks = (wgl >> 2) & 7, kv = wgl >> 5;
    const float* W = kv ? Wv : Wk;
    float (*cs)[128] = (float(*)[128])arena;
    for (int i = t; i < B_ * 128; i += 256)
      cs[i >> 7][i & 127] = ctx[(size_t)(i >> 7) * QD + ks * 128 + (i & 127)];
    __syncthreads();
    int col = ich * 256 + t;
    float a0 = 0, a1 = 0, a2 = 0, a3 = 0;
    for (int k = 0; k < 128; k++) {
      float w = W[(size_t)(ks * 128 + k) * QD + col];
      a0 += cs[0][k] * w; a1 += cs[1][k] * w; a2 += cs[2][k] * w; a3 += cs[3][k] * w;
    }
    float* p = part + (size_t)(ks * 2 + kv) * (B_ * QD);
    p[0 * QD + col] = a0; p[1 * QD + col] = a1; p[2 * QD + col] = a2; p[3 * QD + col] = a3;
  }
}

// ---------------- bf16 GEMM v3 (R18, passing) + optional fused ctx_reduce blocks ----
// WITHRED: blocks wg >= 512 perform the ctx partial reduction (reads `part`,
// writes kctx/vctx) instead of GEMM work -- removes one kernel launch.
template <int BF16OUT, int WRITEQT, int WITHRED>
__global__ __launch_bounds__(256) void k_gemm(const ushort_t* __restrict__ A,
    const ushort_t* __restrict__ Bm, ushort_t* __restrict__ Cb, float* __restrict__ Cf,
    const float* __restrict__ bias, ushort_t* __restrict__ qT,
    const float* __restrict__ part, float* __restrict__ kctx,
    float* __restrict__ vctx) {
  __shared__ __align__(16) char arena[WRITEQT ? (128 * 136 * 2) : (128 * 64 * 2 * 2)];
  ushort_t* As = (ushort_t*)arena;
  ushort_t* Bs = (ushort_t*)arena + 128 * 64;
  const int wg = blockIdx.x;
  const int t = threadIdx.x;
  if constexpr (WITHRED) {
    if (wg >= 512) {
      int idx = (wg - 512) * 256 + t;  // 0..8191
      int kv = idx >> 12;
      int rest = idx & 4095;
      float acc = 0;
#pragma unroll
      for (int ks = 0; ks < 8; ks++) acc += part[(size_t)(ks * 2 + kv) * 4096 + rest];
      (kv ? vctx : kctx)[rest] = acc;
      return;
    }
  }
  const int by = (wg & 7) * 8 + ((wg >> 3) & 7);
  const int bx = wg >> 6;
  const int w = t >> 6, l = t & 63;
  const int wr = w >> 1, wc = w & 1;
  const int lr = l & 15, lg = l >> 4;
  const int m0 = by * 128, n0 = bx * 128;
  f32x4 acc[4][4] = {};
  for (int k0 = 0; k0 < QD; k0 += 64) {
#pragma unroll
    for (int rep = 0; rep < 4; rep++) {
      int c = t + rep * 256;
      int row = c >> 3, c0 = 8 * ((c & 7) ^ (row & 7));
      ldg2lds16(&A[(size_t)(m0 + row) * QD + k0 + c0], &As[c * 8]);
      ldg2lds16(&Bm[(size_t)(n0 + row) * QD + k0 + c0], &Bs[c * 8]);
    }
    __syncthreads();
#pragma unroll
    for (int kk = 0; kk < 2; kk++) {
      bf16x8 af[4], bfr[4];
#pragma unroll
      for (int m = 0; m < 4; m++) {
        int row = wr * 64 + m * 16 + lr;
        af[m] = *(const bf16x8*)((const char*)As + row * 128 +
                                 (((kk * 4 + lg) ^ (row & 7)) << 4));
      }
#pragma unroll
      for (int n = 0; n < 4; n++) {
        int row = wc * 64 + n * 16 + lr;
        bfr[n] = *(const bf16x8*)((const char*)Bs + row * 128 +
                                  (((kk * 4 + lg) ^ (row & 7)) << 4));
      }
#pragma unroll
      for (int m = 0; m < 4; m++)
#pragma unroll
        for (int n = 0; n < 4; n++)
          acc[m][n] = __builtin_amdgcn_mfma_f32_16x16x32_bf16(af[m], bfr[n], acc[m][n], 0, 0, 0);
    }
    __syncthreads();
  }
#pragma unroll
  for (int m = 0; m < 4; m++) {
    int row = m0 + wr * 64 + m * 16 + lg * 4;
#pragma unroll
    for (int n = 0; n < 4; n++) {
      int col = n0 + wc * 64 + n * 16 + lr;
#pragma unroll
      for (int j = 0; j < 4; j++) {
        float v = acc[m][n][j];
        if constexpr (BF16OUT) {
          Cb[(size_t)(row + j) * QD + col] = f2bf(v);
        } else {
          Cf[(size_t)(row + j) * QD + col] = v + bias[col];
        }
      }
    }
  }
  if constexpr (WRITEQT) {
    ushort_t* T2 = (ushort_t*)arena;  // [col][row], stride 136
#pragma unroll
    for (int m = 0; m < 4; m++) {
      int rowl = wr * 64 + m * 16 + lg * 4;
#pragma unroll
      for (int n = 0; n < 4; n++) {
        int col = wc * 64 + n * 16 + lr;
        u16x4 v;
#pragma unroll
        for (int j = 0; j < 4; j++) v[j] = f2bf(acc[m][n][j]);
        *(u16x4*)&T2[col * 136 + rowl] = v;
      }
    }
    __syncthreads();
    const int c = t & 127, r0 = (t >> 7) * 64;
    const int h = (n0 + c) >> 6, d = (n0 + c) & 63;
    const int b = m0 >> 11, nloc = (m0 & 2047) + r0;
    ushort_t* dst = qT + ((size_t)(b * 16 + h) * 64 + d) * (size_t)N_ + nloc;
#pragma unroll
    for (int i = 0; i < 8; i++)
      *(u16x8*)(dst + i * 8) = *(const u16x8*)&T2[c * 136 + r0 + i * 8];
  }
}

// ---------------- flash attention v12 (R16/R18, passing): pre-scaled Q exp2 softmax ----
__global__ __launch_bounds__(256, 2) void k_attn12(
    const ushort_t* __restrict__ q, const ushort_t* __restrict__ qT,
    const float* __restrict__ kctx, const float* __restrict__ vctx,
    ushort_t* __restrict__ att) {
  const int wg = blockIdx.x;
  const int s = wg >> 6;                              // 0..7
  const int bh = ((wg & 7) << 3) | ((wg >> 3) & 7);   // 0..63, XCD-grouped
  const int b = bh >> 4, h = bh & 15;
  const int t = threadIdx.x, w = t >> 6, l = t & 63;
  const int lq = l & 31, hi = l >> 5;

  __shared__ __align__(128) ushort_t Ks[2][2][4096];  // [pair][sub]
  __shared__ __align__(128) ushort_t Vs[2][2][4096];

  const ushort_t* qbase = q + (size_t)b * N_ * QD + h * D_;
  const ushort_t* qtb = qT + (size_t)bh * D_ * N_;
  const float* kc = kctx + bh * D_;
  const float* vc = vctx + bh * D_;

  const int srow = t >> 3;
  const int scol = 8 * ((t & 7) ^ ((t >> 3) & 7));

#pragma unroll 1
  for (int pass = 0; pass < 2; ++pass) {
    const int qt = pass ? 15 - s : s;
    const int i0 = qt * 128;
    const int wq0 = i0 + w * 32;
    const int NI = qt + 1;  // iterations of 2 tiles (NT = 2qt+2)

    __builtin_amdgcn_s_barrier();  // ring-buffer lifetime across passes

    const ushort_t* stK = qbase + (size_t)srow * QD + scol;
    const ushort_t* stV = qtb + (size_t)srow * N_ + scol;

    auto stage = [&](int pr, int j) {
      ldg2lds16(stK, &Ks[pr][j][t * 8]);
      ldg2lds16(stK + (size_t)32 * QD, &Ks[pr][j][(t + 256) * 8]);
      ldg2lds16(stV, &Vs[pr][j][t * 8]);
      ldg2lds16(stV + (size_t)32 * N_, &Vs[pr][j][(t + 256) * 8]);
      stK += (size_t)64 * QD;
      stV += 64;
    };

    stage(0, 0);
    stage(0, 1);

    // Q fragments, pre-scaled by SC2 (logits emerge in exp2-space)
    bf16x8 qf[4];
#pragma unroll
    for (int kk = 0; kk < 4; kk++) {
      qf[kk] = *(const bf16x8*)&qbase[(size_t)(wq0 + lq) * QD + kk * 16 + hi * 8];
#pragma unroll
      for (int j = 0; j < 8; j++)
        qf[kk][j] = (__bf16)((float)qf[kk][j] * SC2);
    }

    float ew, lacc;
    f32x16 oacc[2];
    {
      float dot = 0.f;
#pragma unroll
      for (int kk = 0; kk < 4; kk++)
#pragma unroll
        for (int j = 0; j < 8; j++)
          dot += (float)qf[kk][j] * kc[kk * 16 + hi * 8 + j];
      dot += __shfl_xor(dot, 32);
      ew = __builtin_exp2f(dot);   // ctx token weight (no shift)
      lacc = 0.0f;
#pragma unroll
      for (int dt = 0; dt < 2; dt++)
#pragma unroll
        for (int r = 0; r < 16; r++)
          oacc[dt][r] = vc[dt * 32 + (r & 3) + 8 * (r >> 2) + 4 * hi] * ew;
    }

    auto body = [&](int tt, const char* ksb, const char* vsb) {
      const int j0 = tt * 64;
      if (j0 > wq0 + 31) return;  // wave-level causal skip

      f32x16 p[2];
      __builtin_amdgcn_s_setprio(1);
#pragma unroll
      for (int kb = 0; kb < 2; kb++) {
        f32x16 acc = {};
#pragma unroll
        for (int kk = 0; kk < 4; kk++) {
          bf16x8 kf = *(const bf16x8*)(ksb + (l & 31) * 128 + kb * 4096 +
                                       (((kk * 2 + hi) ^ (l & 7)) << 4));
          acc = __builtin_amdgcn_mfma_f32_32x32x16_bf16(kf, qf[kk], acc, 0, 0, 0);
        }
        p[kb] = acc;
      }
      __builtin_amdgcn_s_setprio(0);

      if (j0 + 63 > wq0) {
        const int qrel = wq0 - j0 + lq;
#pragma unroll
        for (int kb = 0; kb < 2; kb++)
#pragma unroll
          for (int r = 0; r < 16; r++) {
            int key = kb * 32 + (r & 3) + 8 * (r >> 2) + 4 * hi;
            if (key > qrel) p[kb][r] = -1e30f;
          }
      }

      // softmax terms: p already in exp2-space (Q pre-scaled), no shift
#pragma unroll
      for (int kb = 0; kb < 2; kb++)
#pragma unroll
        for (int r = 0; r < 16; r++)
          p[kb][r] = __builtin_exp2f(p[kb][r]);
      float s8[8];
#pragma unroll
      for (int r = 0; r < 8; r++)
        s8[r] = (p[0][r] + p[0][r + 8]) + (p[1][r] + p[1][r + 8]);
      float s4a = s8[0] + s8[4], s4b = s8[1] + s8[5];
      float s4c = s8[2] + s8[6], s4d = s8[3] + s8[7];
      lacc += (s4a + s4b) + (s4c + s4d);

#pragma unroll
      for (int kb = 0; kb < 2; kb++) {
        unsigned u[8];
#pragma unroll
        for (int i = 0; i < 8; i++) {
          float lo = p[kb][2 * i], hi2 = p[kb][2 * i + 1];
          asm("v_cvt_pk_bf16_f32 %0, %1, %2" : "=v"(u[i]) : "v"(lo), "v"(hi2));
        }
        asm("v_permlane32_swap_b32 %0, %1" : "+v"(u[0]), "+v"(u[2]));
        asm("v_permlane32_swap_b32 %0, %1" : "+v"(u[1]), "+v"(u[3]));
        asm("v_permlane32_swap_b32 %0, %1" : "+v"(u[4]), "+v"(u[6]));
        asm("v_permlane32_swap_b32 %0, %1" : "+v"(u[5]), "+v"(u[7]));
        union { unsigned u4[4]; bf16x8 v; } pf0, pf1;
        pf0.u4[0] = u[0]; pf0.u4[1] = u[1]; pf0.u4[2] = u[2]; pf0.u4[3] = u[3];
        pf1.u4[0] = u[4]; pf1.u4[1] = u[5]; pf1.u4[2] = u[6]; pf1.u4[3] = u[7];
        __builtin_amdgcn_s_setprio(1);
#pragma unroll
        for (int ks = 0; ks < 2; ks++) {
          const bf16x8 pf = ks ? pf1.v : pf0.v;
#pragma unroll
          for (int dt = 0; dt < 2; dt++) {
            bf16x8 vf = *(const bf16x8*)(vsb + (l & 31) * 128 + dt * 4096 +
                                         (((kb * 4 + ks * 2 + hi) ^ (l & 7)) << 4));
            oacc[dt] = __builtin_amdgcn_mfma_f32_32x32x16_bf16(vf, pf, oacc[dt], 0, 0, 0);
          }
        }
        __builtin_amdgcn_s_setprio(0);
      }
    };

    for (int it = 0; it < NI; ++it) {
      const int pr = it & 1;
      if (it + 1 < NI) {
        stage(pr ^ 1, 0);
        stage(pr ^ 1, 1);
        asm volatile("s_waitcnt vmcnt(8)" ::: "memory");
      } else {
        asm volatile("s_waitcnt vmcnt(0)" ::: "memory");
      }
      __builtin_amdgcn_s_barrier();

      body(2 * it,     (const char*)&Ks[pr][0][0], (const char*)&Vs[pr][0][0]);
      body(2 * it + 1, (const char*)&Ks[pr][1][0], (const char*)&Vs[pr][1][0]);
    }

    // epilogue: deferred cross-half reduce, then O /= lsum
    const float lsum = ew + lacc + __shfl_xor(lacc, 32);
    const float inv = 1.0f / lsum;
    ushort_t* ob = att + (size_t)b * N_ * QD + (size_t)(wq0 + lq) * QD + h * D_;
#pragma unroll
    for (int dt = 0; dt < 2; dt++)
#pragma unroll
      for (int rq = 0; rq < 4; rq++) {
        union { ushort_t s4[4]; unsigned long long v; } o;
#pragma unroll
        for (int e = 0; e < 4; e++) o.s4[e] = bfbits(oacc[dt][rq * 4 + e] * inv);
        *(unsigned long long*)(ob + dt * 32 + 8 * rq + 4 * hi) = o.v;
      }
  }
}

extern "C" void kernel_launch(void* const* d_in, const int* in_sizes, int n_in,
                              void* d_out, int out_size, void* d_ws, size_t ws_size,
                              hipStream_t stream) {
  const float* x = (const float*)d_in[0];
  const float* ctx = (const float*)d_in[1];
  const float* Wq = (const float*)d_in[2];
  const float* Wk = (const float*)d_in[3];
  const float* Wv = (const float*)d_in[4];
  const float* Wo = (const float*)d_in[5];
  const float* bo = (const float*)d_in[6];
  float* out = (float*)d_out;

  char* ws = (char*)d_ws;
  size_t off = 0;
  ushort_t* xb = (ushort_t*)(ws + off);   off += (size_t)8192 * 1024 * 2;
  ushort_t* qb = (ushort_t*)(ws + off);   off += (size_t)8192 * 1024 * 2;
  ushort_t* attb = (ushort_t*)(ws + off); off += (size_t)8192 * 1024 * 2;
  ushort_t* WqT = (ushort_t*)(ws + off);  off += (size_t)1024 * 1024 * 2;
  ushort_t* WoT = (ushort_t*)(ws + off);  off += (size_t)1024 * 1024 * 2;
  float* kctx = (float*)(ws + off);       off += (size_t)4096 * 4;
  float* vctx = (float*)(ws + off);       off += (size_t)4096 * 4;
  float* part = (float*)(ws + off);       off += (size_t)16 * 4096 * 4;
  ushort_t* qT2 = (ushort_t*)(ws + off);  off += (size_t)8192 * 1024 * 2;

  k_prep<<<dim3(4672), dim3(256), 0, stream>>>(x, xb, Wq, Wo, WqT, WoT,
                                               ctx, Wk, Wv, part);
  k_gemm<1, 1, 1><<<dim3(544), dim3(256), 0, stream>>>(xb, WqT, qb, nullptr, nullptr,
                                                       qT2, part, kctx, vctx);
  k_attn12<<<dim3(512), dim3(256), 0, stream>>>(qb, qT2, kctx, vctx, attb);
  k_gemm<0, 0, 0><<<dim3(512), dim3(256), 0, stream>>>(attb, WoT, nullptr, out, bo,
                                                       nullptr, nullptr, nullptr, nullptr);
}